// Round 3
// baseline (532.784 us; speedup 1.0000x reference)
//
#include <hip/hip_runtime.h>
#include <stdint.h>

// Problem constants (fixed by setup_inputs in the reference)
#define BB 32
#define PP 24564
#define CC 81
#define OO 32

#define V0c 0.1f
#define V1c 0.2f

#define ROWS 32                 // rows per k_ce block (32 -> 13.4KB LDS, 8 blocks/CU)
#define CHUNK (ROWS * CC)       // 2592 floats
#define CHUNK4 (CHUNK / 4)      // 648 float4

// ---------------- workspace layout ----------------
// lc      : float [B*P]
// bp_key  : u64   [B*O]
// ls_slots: float [64]
// cs_slots: float [64]
// num_pos : int   [32]

// ---- DPP rotate-reduce within each 16-lane row (pure VALU, no LDS pipe). ----
// row_ror:n = 0x120|n. Steps 8,4,2,1 leave the reduction in ALL 16 lanes.
template <int CTRL>
__device__ __forceinline__ int dpp_i(int x) {
    return __builtin_amdgcn_update_dpp(0, x, CTRL, 0xF, 0xF, false);
}
template <int CTRL>
__device__ __forceinline__ float dpp_f(float x) {
    return __int_as_float(dpp_i<CTRL>(__float_as_int(x)));
}
__device__ __forceinline__ float rmax16(float v) {
    v = fmaxf(v, dpp_f<0x128>(v));
    v = fmaxf(v, dpp_f<0x124>(v));
    v = fmaxf(v, dpp_f<0x122>(v));
    v = fmaxf(v, dpp_f<0x121>(v));
    return v;
}
__device__ __forceinline__ float rsum16(float v) {
    v += dpp_f<0x128>(v);
    v += dpp_f<0x124>(v);
    v += dpp_f<0x122>(v);
    v += dpp_f<0x121>(v);
    return v;
}
__device__ __forceinline__ int rmax16i(int v) {
    v = max(v, dpp_i<0x128>(v));
    v = max(v, dpp_i<0x124>(v));
    v = max(v, dpp_i<0x122>(v));
    v = max(v, dpp_i<0x121>(v));
    return v;
}
__device__ __forceinline__ int rmin16i(int v) {
    v = min(v, dpp_i<0x128>(v));
    v = min(v, dpp_i<0x124>(v));
    v = min(v, dpp_i<0x122>(v));
    v = min(v, dpp_i<0x121>(v));
    return v;
}

// One block per (o,b): 256 threads stride over all PP priors, block-reduce the
// packed (iou, ~p) key, PLAIN STORE to bp_key (no atomic, no init kernel).
// Block (0,0) also zeroes the accumulator slots (completes before k_ce runs).
__global__ __launch_bounds__(256) void k_bestprior(const float4* __restrict__ priors,
                                                   const float4* __restrict__ boxes,
                                                   unsigned long long* __restrict__ bp_key,
                                                   float* __restrict__ ls_slots,
                                                   float* __restrict__ cs_slots,
                                                   int* __restrict__ num_pos) {
    int o = blockIdx.x;
    int b = blockIdx.y;

    if (o == 0 && b == 0) {
        int t = threadIdx.x;
        if (t < 64) { ls_slots[t] = 0.0f; cs_slots[t] = 0.0f; }
        else if (t < 96) num_pos[t - 64] = 0;
    }

    float4 t = boxes[b * OO + o];
    float area_b = (t.z - t.x) * (t.w - t.y);

    unsigned long long best = 0ULL;
    for (int p = threadIdx.x; p < PP; p += 256) {
        float4 pr = priors[p];
        float ax0 = pr.x - pr.z * 0.5f;
        float ay0 = pr.y - pr.w * 0.5f;
        float ax1 = pr.x + pr.z * 0.5f;
        float ay1 = pr.y + pr.w * 0.5f;
        float area_a = (ax1 - ax0) * (ay1 - ay0);
        float lx = fmaxf(ax0, t.x), ly = fmaxf(ay0, t.y);
        float rx = fminf(ax1, t.z), ry = fminf(ay1, t.w);
        float w = fmaxf(rx - lx, 0.0f), h = fmaxf(ry - ly, 0.0f);
        float inter = w * h;
        float iou = inter / (area_a + area_b - inter);
        unsigned long long key = ((unsigned long long)__float_as_uint(iou) << 32) |
                                 (unsigned long long)(0xFFFFFFFFu - (unsigned int)p);
        best = (key > best) ? key : best;
    }
    #pragma unroll
    for (int off = 32; off; off >>= 1) {
        unsigned long long other = __shfl_down(best, off, 64);
        best = (other > best) ? other : best;
    }
    __shared__ unsigned long long s_w[4];
    int wid = threadIdx.x >> 6;
    if ((threadIdx.x & 63) == 0) s_w[wid] = best;
    __syncthreads();
    if (threadIdx.x == 0) {
        unsigned long long m = s_w[0];
        for (int i = 1; i < 4; ++i) m = (s_w[i] > m) ? s_w[i] : m;
        bp_key[b * OO + o] = m;          // exclusive owner: plain store
    }
}

// Fused match + scatter-override + log-softmax CE + localization loss.
// Block = 32 contiguous rows (13.4KB LDS -> 8 blocks/CU, occupancy ceiling 100%).
// 16-lane group per row; all reductions via DPP (VALU pipe); wave-0 tail.
__global__ __launch_bounds__(256) void k_ce(const float4* __restrict__ conf4,
                                            const float4* __restrict__ loc4,
                                            const float4* __restrict__ priors,
                                            const float4* __restrict__ boxes,
                                            const int* __restrict__ labels,
                                            const unsigned long long* __restrict__ bp_key,
                                            float* __restrict__ lc,
                                            int* __restrict__ num_pos,
                                            float* __restrict__ ls_slots,
                                            float* __restrict__ cs_slots) {
    __shared__ __align__(16) float s_conf[CHUNK];
    __shared__ float4 s_loc[ROWS];
    __shared__ float4 s_pri[ROWS];
    __shared__ float4 s_box[2 * OO];
    __shared__ float s_barea[2 * OO];
    __shared__ int s_lab[2 * OO];
    __shared__ int s_bpp[2 * OO];
    __shared__ float s_ce[ROWS];
    __shared__ float s_ls[ROWS];
    __shared__ int s_pos[ROWS];
    __shared__ float s_lc[ROWS];

    int r0 = blockIdx.x * ROWS;
    int b0 = r0 / PP;
    int split = (b0 + 1) * PP;          // rows >= split belong to b0+1
    int b1 = (b0 + 1 < BB) ? b0 + 1 : b0;
    size_t base4 = (size_t)blockIdx.x * CHUNK4;

    #pragma unroll
    for (int it = 0; it < 3; ++it) {
        int idx = threadIdx.x + 256 * it;
        if (idx < CHUNK4) ((float4*)s_conf)[idx] = conf4[base4 + idx];
    }
    if (threadIdx.x < ROWS) {
        s_loc[threadIdx.x] = loc4[r0 + threadIdx.x];
    } else if (threadIdx.x >= 64 && threadIdx.x < 128) {
        int i = threadIdx.x - 64;        // 0..63: [0,32) = batch b0, [32,64) = b1
        int bb = (i < OO) ? b0 : b1;
        int o = i & (OO - 1);
        float4 t = boxes[bb * OO + o];
        s_box[i] = t;
        s_barea[i] = (t.z - t.x) * (t.w - t.y);
        s_lab[i] = labels[bb * OO + o];
        unsigned long long key = bp_key[bb * OO + o];
        s_bpp[i] = (int)(0xFFFFFFFFu - (unsigned int)(key & 0xFFFFFFFFull));
    } else if (threadIdx.x >= 128 && threadIdx.x < 128 + ROWS) {
        int i = threadIdx.x - 128;       // 0..31: per-row prior
        int r = r0 + i;
        int bb = (r >= split) ? b0 + 1 : b0;
        s_pri[i] = priors[r - bb * PP];
    }
    __syncthreads();

    int g = threadIdx.x >> 4;
    int lane = threadIdx.x & 15;

    #pragma unroll 2
    for (int itr = 0; itr < ROWS / 16; ++itr) {
        int rl = g + 16 * itr;
        int r = r0 + rl;
        int lb = (r >= split) ? 1 : 0;
        int ob = lb << 5;
        int p = r - (b0 + lb) * PP;

        const float* row = s_conf + rl * CC;
        float4 pr = s_pri[rl];           // broadcast LDS read

        float x0 = row[lane];
        float x1 = row[lane + 16];
        float x2 = row[lane + 32];
        float x3 = row[lane + 48];
        float x4 = row[lane + 64];
        float x5 = (lane + 80 < CC) ? row[lane + 80] : -INFINITY;

        float m = fmaxf(fmaxf(fmaxf(x0, x1), fmaxf(x2, x3)), fmaxf(x4, x5));
        m = rmax16(m);
        float sum = __expf(x0 - m) + __expf(x1 - m) + __expf(x2 - m) +
                    __expf(x3 - m) + __expf(x4 - m) + __expf(x5 - m);
        sum = rsum16(sum);
        float lse = __logf(sum) + m;

        // inline best-truth match: 2 boxes per lane, DPP reduce (first-max wins)
        float ax0 = pr.x - pr.z * 0.5f;
        float ay0 = pr.y - pr.w * 0.5f;
        float ax1 = pr.x + pr.z * 0.5f;
        float ay1 = pr.y + pr.w * 0.5f;
        float area_a = (ax1 - ax0) * (ay1 - ay0);

        float4 t1 = s_box[ob + lane];
        float4 t2 = s_box[ob + lane + 16];
        float lx = fmaxf(ax0, t1.x), ly = fmaxf(ay0, t1.y);
        float rx = fminf(ax1, t1.z), ry = fminf(ay1, t1.w);
        float w = fmaxf(rx - lx, 0.0f), h = fmaxf(ry - ly, 0.0f);
        float inter = w * h;
        float i1 = inter / (area_a + s_barea[ob + lane] - inter);
        lx = fmaxf(ax0, t2.x); ly = fmaxf(ay0, t2.y);
        rx = fminf(ax1, t2.z); ry = fminf(ay1, t2.w);
        w = fmaxf(rx - lx, 0.0f); h = fmaxf(ry - ly, 0.0f);
        inter = w * h;
        float i2 = inter / (area_a + s_barea[ob + lane + 16] - inter);

        float biou = rmax16(fmaxf(i1, i2));
        int cand = (i1 == biou) ? lane : ((i2 == biou) ? (lane + 16) : (1 << 30));
        cand = rmin16i(cand);            // first (lowest-o) max, as in argmax

        // best-prior override: largest matching o wins (serial-scatter semantics)
        int co = -1;
        if (s_bpp[ob + lane] == p) co = lane;
        if (s_bpp[ob + lane + 16] == p) co = lane + 16;
        co = rmax16i(co);

        int tt = cand;
        float ov = biou;
        if (co >= 0) { tt = co; ov = 2.0f; }
        tt &= 31;                        // hardening: never index OOB

        int cls = s_lab[ob + tt];
        if (ov < 0.5f) cls = 0;
        float ce = lse - row[cls];       // broadcast LDS read
        bool pos = cls > 0;

        if (lane == 0) {
            s_lc[rl] = pos ? 0.0f : ce;
            s_ce[rl] = pos ? ce : 0.0f;
            float s = 0.0f;
            if (pos) {
                float4 tb = s_box[ob + tt];
                float4 lp = s_loc[rl];
                float gx = ((tb.x + tb.z) * 0.5f - pr.x) / (V0c * pr.z);
                float gy = ((tb.y + tb.w) * 0.5f - pr.y) / (V0c * pr.w);
                float gw = logf((tb.z - tb.x) / pr.z) / V1c;
                float gh = logf((tb.w - tb.y) / pr.w) / V1c;
                float d0 = fabsf(lp.x - gx);
                float d1 = fabsf(lp.y - gy);
                float d2 = fabsf(lp.z - gw);
                float d3 = fabsf(lp.w - gh);
                s += (d0 < 1.0f) ? 0.5f * d0 * d0 : d0 - 0.5f;
                s += (d1 < 1.0f) ? 0.5f * d1 * d1 : d1 - 0.5f;
                s += (d2 < 1.0f) ? 0.5f * d2 * d2 : d2 - 0.5f;
                s += (d3 < 1.0f) ? 0.5f * d3 * d3 : d3 - 0.5f;
            }
            s_ls[rl] = s;
            s_pos[rl] = pos ? (1 + lb) : 0;
        }
    }
    __syncthreads();

    // parallel tail: lanes 0..31 of wave 0 tree-reduce the 32 rows
    if (threadIdx.x < ROWS) {
        int i = threadIdx.x;
        lc[r0 + i] = s_lc[i];            // coalesced
        float ces = s_ce[i];
        float lss = s_ls[i];
        int pv = s_pos[i];
        int cnt = (pv == 1) | ((int)(pv == 2) << 10);
        #pragma unroll
        for (int off = 16; off; off >>= 1) {
            ces += __shfl_down(ces, off, 64);
            lss += __shfl_down(lss, off, 64);
            cnt += __shfl_down(cnt, off, 64);
        }
        if (i == 0) {
            int c0 = cnt & 1023, c1 = cnt >> 10;
            if (c0) atomicAdd(&num_pos[b0], c0);
            if (c1) atomicAdd(&num_pos[b0 + 1], c1);
            if (c0 + c1) {
                int sl = blockIdx.x & 63;
                atomicAdd(&ls_slots[sl], lss);
                atomicAdd(&cs_slots[sl], ces);
            }
        }
    }
}

// One block per batch: exact top-k sum of lc via 31-bit MSB radix select.
__global__ __launch_bounds__(1024) void k_select(const float* __restrict__ lc,
                                                 const int* __restrict__ num_pos,
                                                 float* __restrict__ cs_slots) {
    int b = blockIdx.x;
    const float* v = lc + (size_t)b * PP;
    int np = num_pos[b];
    long long k0 = 3LL * (long long)np;
    int k = (k0 < (long long)(PP - 1)) ? (int)k0 : (PP - 1);

    __shared__ int s_cnt[16];
    __shared__ float s_sum[16];
    __shared__ unsigned int s_prefix;
    __shared__ int s_k;

    unsigned int val[24];
    #pragma unroll
    for (int i = 0; i < 24; ++i) {
        int idx = threadIdx.x + i * 1024;
        val[i] = (idx < PP) ? __float_as_uint(v[idx]) : 0u;
    }

    if (k <= 0) return;  // uniform per block

    if (threadIdx.x == 0) { s_prefix = 0u; s_k = k; }
    __syncthreads();

    unsigned int prefix = 0u;
    for (int bit = 30; bit >= 0; --bit) {
        unsigned int cand = prefix | (1u << bit);
        unsigned int hi = cand >> bit;
        int c = 0;
        #pragma unroll
        for (int i = 0; i < 24; ++i) c += ((val[i] >> bit) == hi);
        #pragma unroll
        for (int off = 32; off; off >>= 1) c += __shfl_down(c, off, 64);
        int wid = threadIdx.x >> 6;
        if ((threadIdx.x & 63) == 0) s_cnt[wid] = c;
        __syncthreads();
        if (threadIdx.x == 0) {
            int tot = 0;
            #pragma unroll
            for (int i = 0; i < 16; ++i) tot += s_cnt[i];
            if (tot >= s_k) s_prefix = cand; else s_k -= tot;
        }
        __syncthreads();
        prefix = s_prefix;
    }

    float fv = __uint_as_float(prefix);
    float ssum = 0.0f;
    int cgt = 0;
    #pragma unroll
    for (int i = 0; i < 24; ++i) {
        if (val[i] > prefix) { ssum += __uint_as_float(val[i]); cgt++; }
    }
    #pragma unroll
    for (int off = 32; off; off >>= 1) {
        ssum += __shfl_down(ssum, off, 64);
        cgt += __shfl_down(cgt, off, 64);
    }
    int wid = threadIdx.x >> 6;
    if ((threadIdx.x & 63) == 0) { s_cnt[wid] = cgt; s_sum[wid] = ssum; }
    __syncthreads();
    if (threadIdx.x == 0) {
        int ct = 0;
        float st = 0.0f;
        #pragma unroll
        for (int i = 0; i < 16; ++i) { ct += s_cnt[i]; st += s_sum[i]; }
        float topk = st + (float)(k - ct) * fv;
        atomicAdd(&cs_slots[b], topk);  // b < 32: spread, 1 atomic/block
    }
}

__global__ void k_final(const int* __restrict__ num_pos,
                        const float* __restrict__ ls_slots,
                        const float* __restrict__ cs_slots,
                        float* __restrict__ out) {
    if (threadIdx.x == 0 && blockIdx.x == 0) {
        int N = 0;
        for (int b = 0; b < BB; ++b) N += num_pos[b];
        float Sl = 0.0f, Sc = 0.0f;
        for (int i = 0; i < 64; ++i) { Sl += ls_slots[i]; Sc += cs_slots[i]; }
        float fN = (float)N;
        out[0] = Sl / fN + Sc / fN;
    }
}

extern "C" void kernel_launch(void* const* d_in, const int* in_sizes, int n_in,
                              void* d_out, int out_size, void* d_ws, size_t ws_size,
                              hipStream_t stream) {
    const float* loc_preds = (const float*)d_in[0];   // [B,P,4]
    const float* conf_preds = (const float*)d_in[1];  // [B,P,C]
    const float* priors = (const float*)d_in[2];      // [P,4] center form
    const float* boxes = (const float*)d_in[3];       // [B,O,4] corner form
    const int* labels = (const int*)d_in[4];          // [B,O]

    char* ws = (char*)d_ws;
    const size_t SZ_BP = (size_t)BB * PP;
    float* lc = (float*)ws;
    unsigned long long* bp_key = (unsigned long long*)(ws + SZ_BP * 4);
    float* ls_slots = (float*)(ws + SZ_BP * 4 + (size_t)BB * OO * 8);
    float* cs_slots = ls_slots + 64;
    int* num_pos = (int*)(cs_slots + 64);

    dim3 g2(OO, BB);
    k_bestprior<<<g2, 256, 0, stream>>>((const float4*)priors, (const float4*)boxes,
                                        bp_key, ls_slots, cs_slots, num_pos);

    int rows = BB * PP;
    k_ce<<<rows / ROWS, 256, 0, stream>>>((const float4*)conf_preds,
                                          (const float4*)loc_preds,
                                          (const float4*)priors, (const float4*)boxes,
                                          labels, bp_key, lc, num_pos,
                                          ls_slots, cs_slots);

    k_select<<<BB, 1024, 0, stream>>>(lc, num_pos, cs_slots);

    k_final<<<1, 64, 0, stream>>>(num_pos, ls_slots, cs_slots, (float*)d_out);
}

// Round 4
// 462.032 us; speedup vs baseline: 1.1531x; 1.1531x over previous
//
#include <hip/hip_runtime.h>
#include <stdint.h>

// Problem constants (fixed by setup_inputs in the reference)
#define BB 32
#define PP 24564
#define CC 81
#define OO 32

#define V0c 0.1f
#define V1c 0.2f

#define ROWS 64                 // rows per k_ce block

// ---------------- workspace layout ----------------
// lc      : float [B*P]
// bp_key  : u64   [B*O]
// ls_slots: float [64]
// cs_slots: float [64]
// num_pos : int   [32]

// ---- DPP rotate-reduce within each 16-lane row (pure VALU, no LDS pipe). ----
// row_ror:n = 0x120|n. Steps 8,4,2,1 leave the reduction in ALL 16 lanes.
template <int CTRL>
__device__ __forceinline__ int dpp_i(int x) {
    return __builtin_amdgcn_update_dpp(0, x, CTRL, 0xF, 0xF, false);
}
template <int CTRL>
__device__ __forceinline__ float dpp_f(float x) {
    return __int_as_float(dpp_i<CTRL>(__float_as_int(x)));
}
__device__ __forceinline__ float rmax16(float v) {
    v = fmaxf(v, dpp_f<0x128>(v));
    v = fmaxf(v, dpp_f<0x124>(v));
    v = fmaxf(v, dpp_f<0x122>(v));
    v = fmaxf(v, dpp_f<0x121>(v));
    return v;
}
__device__ __forceinline__ float rsum16(float v) {
    v += dpp_f<0x128>(v);
    v += dpp_f<0x124>(v);
    v += dpp_f<0x122>(v);
    v += dpp_f<0x121>(v);
    return v;
}
__device__ __forceinline__ int rmax16i(int v) {
    v = max(v, dpp_i<0x128>(v));
    v = max(v, dpp_i<0x124>(v));
    v = max(v, dpp_i<0x122>(v));
    v = max(v, dpp_i<0x121>(v));
    return v;
}
__device__ __forceinline__ int rmin16i(int v) {
    v = min(v, dpp_i<0x128>(v));
    v = min(v, dpp_i<0x124>(v));
    v = min(v, dpp_i<0x122>(v));
    v = min(v, dpp_i<0x121>(v));
    return v;
}

__global__ void k_init(unsigned long long* bp_key, float* ls_slots, float* cs_slots,
                       int* num_pos) {
    int i = blockIdx.x * 256 + threadIdx.x;
    if (i < BB * OO) bp_key[i] = 0ULL;
    if (i < 64) { ls_slots[i] = 0.0f; cs_slots[i] = 0.0f; }
    if (i < BB) num_pos[i] = 0;
}

// Grid (O, B, 8): each block scans 1/8 of priors for one (b,o); global atomicMax
// on packed (iou, ~p) key merges segments. 8 atomics per address total.
__global__ __launch_bounds__(256) void k_bestprior(const float4* __restrict__ priors,
                                                   const float4* __restrict__ boxes,
                                                   unsigned long long* __restrict__ bp_key) {
    int o = blockIdx.x;
    int b = blockIdx.y;
    const int NSEG = 8;
    const int SEG = (PP + NSEG - 1) / NSEG;
    int p0 = blockIdx.z * SEG;
    int p1 = p0 + SEG;
    if (p1 > PP) p1 = PP;

    float4 t = boxes[b * OO + o];
    float area_b = (t.z - t.x) * (t.w - t.y);

    unsigned long long best = 0ULL;
    for (int p = p0 + threadIdx.x; p < p1; p += 256) {
        float4 pr = priors[p];
        float ax0 = pr.x - pr.z * 0.5f;
        float ay0 = pr.y - pr.w * 0.5f;
        float ax1 = pr.x + pr.z * 0.5f;
        float ay1 = pr.y + pr.w * 0.5f;
        float area_a = (ax1 - ax0) * (ay1 - ay0);
        float lx = fmaxf(ax0, t.x), ly = fmaxf(ay0, t.y);
        float rx = fminf(ax1, t.z), ry = fminf(ay1, t.w);
        float w = fmaxf(rx - lx, 0.0f), h = fmaxf(ry - ly, 0.0f);
        float inter = w * h;
        float iou = inter / (area_a + area_b - inter);
        unsigned long long key = ((unsigned long long)__float_as_uint(iou) << 32) |
                                 (unsigned long long)(0xFFFFFFFFu - (unsigned int)p);
        best = (key > best) ? key : best;
    }
    #pragma unroll
    for (int off = 32; off; off >>= 1) {
        unsigned long long other = __shfl_down(best, off, 64);
        best = (other > best) ? other : best;
    }
    __shared__ unsigned long long s_w[4];
    int wid = threadIdx.x >> 6;
    if ((threadIdx.x & 63) == 0) s_w[wid] = best;
    __syncthreads();
    if (threadIdx.x == 0) {
        unsigned long long m = s_w[0];
        for (int i = 1; i < 4; ++i) m = (s_w[i] > m) ? s_w[i] : m;
        atomicMax(&bp_key[b * OO + o], m);
    }
}

// Fused match + scatter-override + log-softmax CE + localization loss.
// Block = 64 contiguous rows. Conf is read DIRECTLY from global to registers
// (stride-16 per lane -> 64B-coalesced sectors; row-tail sectors reused by the
// next row via L1/L2). No conf LDS buffer: ~5.3KB LDS -> 8 blocks/CU.
// 16-lane group per row; all reductions via DPP (VALU pipe); wave-0 tail.
__global__ __launch_bounds__(256, 8) void k_ce(const float* __restrict__ conf,
                                               const float4* __restrict__ loc4,
                                               const float4* __restrict__ priors,
                                               const float4* __restrict__ boxes,
                                               const int* __restrict__ labels,
                                               const unsigned long long* __restrict__ bp_key,
                                               float* __restrict__ lc,
                                               int* __restrict__ num_pos,
                                               float* __restrict__ ls_slots,
                                               float* __restrict__ cs_slots) {
    __shared__ float4 s_loc[ROWS];
    __shared__ float4 s_pri[ROWS];
    __shared__ float4 s_box[2 * OO];
    __shared__ float s_barea[2 * OO];
    __shared__ int s_lab[2 * OO];
    __shared__ int s_bpp[2 * OO];
    __shared__ float s_ce[ROWS];
    __shared__ float s_ls[ROWS];
    __shared__ int s_pos[ROWS];
    __shared__ float s_lc[ROWS];

    int r0 = blockIdx.x * ROWS;
    int b0 = r0 / PP;
    int split = (b0 + 1) * PP;          // rows >= split belong to b0+1
    int b1 = (b0 + 1 < BB) ? b0 + 1 : b0;

    if (threadIdx.x < ROWS) {
        s_loc[threadIdx.x] = loc4[r0 + threadIdx.x];
    } else if (threadIdx.x < 128) {
        int i = threadIdx.x - 64;        // 0..63: [0,32) = batch b0, [32,64) = b1
        int bb = (i < OO) ? b0 : b1;
        int o = i & (OO - 1);
        float4 t = boxes[bb * OO + o];
        s_box[i] = t;
        s_barea[i] = (t.z - t.x) * (t.w - t.y);
        s_lab[i] = labels[bb * OO + o];
        unsigned long long key = bp_key[bb * OO + o];
        s_bpp[i] = (int)(0xFFFFFFFFu - (unsigned int)(key & 0xFFFFFFFFull));
    } else if (threadIdx.x < 192) {
        int i = threadIdx.x - 128;       // 0..63: per-row prior
        int r = r0 + i;
        int bb = (r >= split) ? b0 + 1 : b0;
        s_pri[i] = priors[r - bb * PP];
    }
    __syncthreads();

    int g = threadIdx.x >> 4;
    int lane = threadIdx.x & 15;

    #pragma unroll 2
    for (int itr = 0; itr < ROWS / 16; ++itr) {
        int rl = g + 16 * itr;
        int r = r0 + rl;
        int lb = (r >= split) ? 1 : 0;
        int ob = lb << 5;
        int p = r - (b0 + lb) * PP;

        const float* row = conf + (size_t)r * CC;   // direct global, 64B sectors
        float4 pr = s_pri[rl];           // broadcast LDS read

        float x0 = row[lane];
        float x1 = row[lane + 16];
        float x2 = row[lane + 32];
        float x3 = row[lane + 48];
        float x4 = row[lane + 64];
        float x5 = (lane + 80 < CC) ? row[lane + 80] : -INFINITY;

        float m = fmaxf(fmaxf(fmaxf(x0, x1), fmaxf(x2, x3)), fmaxf(x4, x5));
        m = rmax16(m);
        float sum = __expf(x0 - m) + __expf(x1 - m) + __expf(x2 - m) +
                    __expf(x3 - m) + __expf(x4 - m) + __expf(x5 - m);
        sum = rsum16(sum);
        float lse = __logf(sum) + m;

        // inline best-truth match: 2 boxes per lane, DPP reduce (first-max wins)
        float ax0 = pr.x - pr.z * 0.5f;
        float ay0 = pr.y - pr.w * 0.5f;
        float ax1 = pr.x + pr.z * 0.5f;
        float ay1 = pr.y + pr.w * 0.5f;
        float area_a = (ax1 - ax0) * (ay1 - ay0);

        float4 t1 = s_box[ob + lane];
        float4 t2 = s_box[ob + lane + 16];
        float lx = fmaxf(ax0, t1.x), ly = fmaxf(ay0, t1.y);
        float rx = fminf(ax1, t1.z), ry = fminf(ay1, t1.w);
        float w = fmaxf(rx - lx, 0.0f), h = fmaxf(ry - ly, 0.0f);
        float inter = w * h;
        float i1 = inter / (area_a + s_barea[ob + lane] - inter);
        lx = fmaxf(ax0, t2.x); ly = fmaxf(ay0, t2.y);
        rx = fminf(ax1, t2.z); ry = fminf(ay1, t2.w);
        w = fmaxf(rx - lx, 0.0f); h = fmaxf(ry - ly, 0.0f);
        inter = w * h;
        float i2 = inter / (area_a + s_barea[ob + lane + 16] - inter);

        float biou = rmax16(fmaxf(i1, i2));
        int cand = (i1 == biou) ? lane : ((i2 == biou) ? (lane + 16) : (1 << 30));
        cand = rmin16i(cand);            // first (lowest-o) max, as in argmax

        // best-prior override: largest matching o wins (serial-scatter semantics)
        int co = -1;
        if (s_bpp[ob + lane] == p) co = lane;
        if (s_bpp[ob + lane + 16] == p) co = lane + 16;
        co = rmax16i(co);

        int tt = cand;
        float ov = biou;
        if (co >= 0) { tt = co; ov = 2.0f; }
        tt &= 31;                        // hardening: never index OOB

        int cls = s_lab[ob + tt];
        if (ov < 0.5f) cls = 0;

        // fetch x[cls] from registers: slot select + 16-wide shuffle
        int slot = cls >> 4;
        float xs = x0;
        xs = (slot == 1) ? x1 : xs;
        xs = (slot == 2) ? x2 : xs;
        xs = (slot == 3) ? x3 : xs;
        xs = (slot == 4) ? x4 : xs;
        xs = (slot == 5) ? x5 : xs;
        float xt = __shfl(xs, cls & 15, 16);
        float ce = lse - xt;
        bool pos = cls > 0;

        if (lane == 0) {
            s_lc[rl] = pos ? 0.0f : ce;
            s_ce[rl] = pos ? ce : 0.0f;
            float s = 0.0f;
            if (pos) {
                float4 tb = s_box[ob + tt];
                float4 lp = s_loc[rl];
                float gx = ((tb.x + tb.z) * 0.5f - pr.x) / (V0c * pr.z);
                float gy = ((tb.y + tb.w) * 0.5f - pr.y) / (V0c * pr.w);
                float gw = logf((tb.z - tb.x) / pr.z) / V1c;
                float gh = logf((tb.w - tb.y) / pr.w) / V1c;
                float d0 = fabsf(lp.x - gx);
                float d1 = fabsf(lp.y - gy);
                float d2 = fabsf(lp.z - gw);
                float d3 = fabsf(lp.w - gh);
                s += (d0 < 1.0f) ? 0.5f * d0 * d0 : d0 - 0.5f;
                s += (d1 < 1.0f) ? 0.5f * d1 * d1 : d1 - 0.5f;
                s += (d2 < 1.0f) ? 0.5f * d2 * d2 : d2 - 0.5f;
                s += (d3 < 1.0f) ? 0.5f * d3 * d3 : d3 - 0.5f;
            }
            s_ls[rl] = s;
            s_pos[rl] = pos ? (1 + lb) : 0;
        }
    }
    __syncthreads();

    // parallel tail: wave 0 tree-reduces the 64 rows
    if (threadIdx.x < 64) {
        int i = threadIdx.x;
        lc[r0 + i] = s_lc[i];            // coalesced
        float ces = s_ce[i];
        float lss = s_ls[i];
        int pv = s_pos[i];
        int cnt = (pv == 1) | ((int)(pv == 2) << 10);
        #pragma unroll
        for (int off = 32; off; off >>= 1) {
            ces += __shfl_down(ces, off, 64);
            lss += __shfl_down(lss, off, 64);
            cnt += __shfl_down(cnt, off, 64);
        }
        if (i == 0) {
            int c0 = cnt & 1023, c1 = cnt >> 10;
            if (c0) atomicAdd(&num_pos[b0], c0);
            if (c1) atomicAdd(&num_pos[b0 + 1], c1);
            if (c0 + c1) {
                int sl = blockIdx.x & 63;
                atomicAdd(&ls_slots[sl], lss);
                atomicAdd(&cs_slots[sl], ces);
            }
        }
    }
}

// One block per batch: exact top-k sum of lc via 31-bit MSB radix select.
__global__ __launch_bounds__(1024) void k_select(const float* __restrict__ lc,
                                                 const int* __restrict__ num_pos,
                                                 float* __restrict__ cs_slots) {
    int b = blockIdx.x;
    const float* v = lc + (size_t)b * PP;
    int np = num_pos[b];
    long long k0 = 3LL * (long long)np;
    int k = (k0 < (long long)(PP - 1)) ? (int)k0 : (PP - 1);

    __shared__ int s_cnt[16];
    __shared__ float s_sum[16];
    __shared__ unsigned int s_prefix;
    __shared__ int s_k;

    unsigned int val[24];
    #pragma unroll
    for (int i = 0; i < 24; ++i) {
        int idx = threadIdx.x + i * 1024;
        val[i] = (idx < PP) ? __float_as_uint(v[idx]) : 0u;
    }

    if (k <= 0) return;  // uniform per block

    if (threadIdx.x == 0) { s_prefix = 0u; s_k = k; }
    __syncthreads();

    unsigned int prefix = 0u;
    for (int bit = 30; bit >= 0; --bit) {
        unsigned int cand = prefix | (1u << bit);
        unsigned int hi = cand >> bit;
        int c = 0;
        #pragma unroll
        for (int i = 0; i < 24; ++i) c += ((val[i] >> bit) == hi);
        #pragma unroll
        for (int off = 32; off; off >>= 1) c += __shfl_down(c, off, 64);
        int wid = threadIdx.x >> 6;
        if ((threadIdx.x & 63) == 0) s_cnt[wid] = c;
        __syncthreads();
        if (threadIdx.x == 0) {
            int tot = 0;
            #pragma unroll
            for (int i = 0; i < 16; ++i) tot += s_cnt[i];
            if (tot >= s_k) s_prefix = cand; else s_k -= tot;
        }
        __syncthreads();
        prefix = s_prefix;
    }

    float fv = __uint_as_float(prefix);
    float ssum = 0.0f;
    int cgt = 0;
    #pragma unroll
    for (int i = 0; i < 24; ++i) {
        if (val[i] > prefix) { ssum += __uint_as_float(val[i]); cgt++; }
    }
    #pragma unroll
    for (int off = 32; off; off >>= 1) {
        ssum += __shfl_down(ssum, off, 64);
        cgt += __shfl_down(cgt, off, 64);
    }
    int wid = threadIdx.x >> 6;
    if ((threadIdx.x & 63) == 0) { s_cnt[wid] = cgt; s_sum[wid] = ssum; }
    __syncthreads();
    if (threadIdx.x == 0) {
        int ct = 0;
        float st = 0.0f;
        #pragma unroll
        for (int i = 0; i < 16; ++i) { ct += s_cnt[i]; st += s_sum[i]; }
        float topk = st + (float)(k - ct) * fv;
        atomicAdd(&cs_slots[b], topk);  // b < 32: spread, 1 atomic/block
    }
}

__global__ void k_final(const int* __restrict__ num_pos,
                        const float* __restrict__ ls_slots,
                        const float* __restrict__ cs_slots,
                        float* __restrict__ out) {
    if (threadIdx.x == 0 && blockIdx.x == 0) {
        int N = 0;
        for (int b = 0; b < BB; ++b) N += num_pos[b];
        float Sl = 0.0f, Sc = 0.0f;
        for (int i = 0; i < 64; ++i) { Sl += ls_slots[i]; Sc += cs_slots[i]; }
        float fN = (float)N;
        out[0] = Sl / fN + Sc / fN;
    }
}

extern "C" void kernel_launch(void* const* d_in, const int* in_sizes, int n_in,
                              void* d_out, int out_size, void* d_ws, size_t ws_size,
                              hipStream_t stream) {
    const float* loc_preds = (const float*)d_in[0];   // [B,P,4]
    const float* conf_preds = (const float*)d_in[1];  // [B,P,C]
    const float* priors = (const float*)d_in[2];      // [P,4] center form
    const float* boxes = (const float*)d_in[3];       // [B,O,4] corner form
    const int* labels = (const int*)d_in[4];          // [B,O]

    char* ws = (char*)d_ws;
    const size_t SZ_BP = (size_t)BB * PP;
    float* lc = (float*)ws;
    unsigned long long* bp_key = (unsigned long long*)(ws + SZ_BP * 4);
    float* ls_slots = (float*)(ws + SZ_BP * 4 + (size_t)BB * OO * 8);
    float* cs_slots = ls_slots + 64;
    int* num_pos = (int*)(cs_slots + 64);

    k_init<<<4, 256, 0, stream>>>(bp_key, ls_slots, cs_slots, num_pos);

    dim3 g2(OO, BB, 8);
    k_bestprior<<<g2, 256, 0, stream>>>((const float4*)priors, (const float4*)boxes,
                                        bp_key);

    int rows = BB * PP;
    k_ce<<<rows / ROWS, 256, 0, stream>>>(conf_preds,
                                          (const float4*)loc_preds,
                                          (const float4*)priors, (const float4*)boxes,
                                          labels, bp_key, lc, num_pos,
                                          ls_slots, cs_slots);

    k_select<<<BB, 1024, 0, stream>>>(lc, num_pos, cs_slots);

    k_final<<<1, 64, 0, stream>>>(num_pos, ls_slots, cs_slots, (float*)d_out);
}